// Round 1
// baseline (708.119 us; speedup 1.0000x reference)
//
#include <hip/hip_runtime.h>
#include <cstdint>
#include <cstddef>

#define LRELU(x) ((x) > 0.f ? (x) : 0.2f*(x))

__device__ __forceinline__ float wave_reduce(float v) {
  #pragma unroll
  for (int m = 32; m > 0; m >>= 1) v += __shfl_xor(v, m, 64);
  return v;
}

// ---------------- tiled f32 GEMM: C[M,N] = A[M,K] @ B[K,N] (+bias)(+relu) ----
template<bool RELU, bool BIAS>
__global__ __launch_bounds__(256) void gemm64(const float* __restrict__ A,
    const float* __restrict__ Bm, const float* __restrict__ bias,
    float* __restrict__ C, int M, int N, int K) {
  __shared__ float As[32][68];   // A tile transposed: As[k][row]
  __shared__ float Bs[32][68];   // Bs[k][col]
  const int tid = threadIdx.x;
  const int tx = tid & 15, ty = tid >> 4;
  const int r0 = blockIdx.x * 64, c0 = blockIdx.y * 64;
  float acc[4][4] = {};
  for (int k0 = 0; k0 < K; k0 += 32) {
    #pragma unroll
    for (int i = 0; i < 2; i++) {            // 512 float4 for A tile
      int f = tid + i * 256;
      int row = f >> 3, k4 = (f & 7) << 2;
      float4 v = make_float4(0.f, 0.f, 0.f, 0.f);
      int gr = r0 + row;
      if (gr < M) v = *(const float4*)(A + (size_t)gr * K + k0 + k4);
      As[k4 + 0][row] = v.x; As[k4 + 1][row] = v.y;
      As[k4 + 2][row] = v.z; As[k4 + 3][row] = v.w;
    }
    #pragma unroll
    for (int i = 0; i < 2; i++) {            // 512 float4 for B tile
      int f = tid + i * 256;
      int kr = f >> 4, c4 = (f & 15) << 2;
      float4 v = *(const float4*)(Bm + (size_t)(k0 + kr) * N + c0 + c4);
      *(float4*)&Bs[kr][c4] = v;
    }
    __syncthreads();
    #pragma unroll
    for (int kk = 0; kk < 32; kk++) {
      float4 a4 = *(const float4*)&As[kk][ty << 2];
      float4 b4 = *(const float4*)&Bs[kk][tx << 2];
      float av[4] = {a4.x, a4.y, a4.z, a4.w};
      float bv[4] = {b4.x, b4.y, b4.z, b4.w};
      #pragma unroll
      for (int i = 0; i < 4; i++)
        #pragma unroll
        for (int j = 0; j < 4; j++)
          acc[i][j] = fmaf(av[i], bv[j], acc[i][j]);
    }
    __syncthreads();
  }
  #pragma unroll
  for (int i = 0; i < 4; i++) {
    int r = r0 + (ty << 2) + i;
    if (r >= M) continue;
    int c = c0 + (tx << 2);
    float4 o = make_float4(acc[i][0], acc[i][1], acc[i][2], acc[i][3]);
    if (BIAS) { o.x += bias[c]; o.y += bias[c+1]; o.z += bias[c+2]; o.w += bias[c+3]; }
    if (RELU) {
      o.x = fmaxf(o.x, 0.f); o.y = fmaxf(o.y, 0.f);
      o.z = fmaxf(o.z, 0.f); o.w = fmaxf(o.w, 0.f);
    }
    *(float4*)(C + (size_t)r * N + c) = o;
  }
}

// ------------- per-node attention coefficients for layer 1 ------------------
// a_src[n,h] = dot(h1[n,h,:], att_src[h,:]) ; likewise dst. Wave per node.
__global__ __launch_bounds__(256) void a1_kernel(const float* __restrict__ h1,
    const float* __restrict__ atts, const float* __restrict__ attd,
    float* __restrict__ a1s, float* __restrict__ a1d, int n) {
  int wid = (blockIdx.x * 256 + threadIdx.x) >> 6;
  int lane = threadIdx.x & 63;
  if (wid >= n) return;
  const float* hp = h1 + (size_t)wid * 192;
  #pragma unroll
  for (int h = 0; h < 3; h++) {
    float hv = hp[h * 64 + lane];
    float ps = wave_reduce(hv * atts[h * 64 + lane]);
    float pd = wave_reduce(hv * attd[h * 64 + lane]);
    if (lane == 0) { a1s[wid * 3 + h] = ps; a1d[wid * 3 + h] = pd; }
  }
}

// ---------------- CSR build (shared by both GAT layers) ---------------------
__global__ void edge_count(const int* __restrict__ dst, int* __restrict__ deg,
                           int E, int Etot) {
  int e = blockIdx.x * 256 + threadIdx.x;
  if (e >= Etot) return;
  int d = (e < E) ? dst[e] : (e - E);
  atomicAdd(&deg[d], 1);
}

__global__ void scan1(const int* __restrict__ deg, int* __restrict__ excl,
                      int* __restrict__ bsum, int n) {
  __shared__ int sh[256];
  int t = threadIdx.x;
  int idx = blockIdx.x * 256 + t;
  int v = (idx < n) ? deg[idx] : 0;
  sh[t] = v;
  __syncthreads();
  for (int ofs = 1; ofs < 256; ofs <<= 1) {
    int add = (t >= ofs) ? sh[t - ofs] : 0;
    __syncthreads();
    sh[t] += add;
    __syncthreads();
  }
  if (idx < n) excl[idx] = sh[t] - v;
  if (t == 255) bsum[blockIdx.x] = sh[255];
}

__global__ void scan2(const int* __restrict__ bsum, int* __restrict__ boff, int nb) {
  __shared__ int sh[512];
  int t = threadIdx.x;
  int v = (t < nb) ? bsum[t] : 0;
  sh[t] = v;
  __syncthreads();
  for (int ofs = 1; ofs < 512; ofs <<= 1) {
    int add = (t >= ofs) ? sh[t - ofs] : 0;
    __syncthreads();
    sh[t] += add;
    __syncthreads();
  }
  if (t < nb) boff[t] = sh[t] - v;
}

__global__ void scan3(const int* __restrict__ excl, const int* __restrict__ boff,
                      int* __restrict__ off, int* __restrict__ cursor, int n, int etot) {
  int idx = blockIdx.x * 256 + threadIdx.x;
  if (idx < n) {
    int o = excl[idx] + boff[blockIdx.x];
    off[idx] = o;
    cursor[idx] = o;
  }
  if (idx == 0) off[n] = etot;
}

__global__ void edge_fill(const int* __restrict__ src, const int* __restrict__ dst,
                          int* __restrict__ cursor, int* __restrict__ csr,
                          int E, int Etot) {
  int e = blockIdx.x * 256 + threadIdx.x;
  if (e >= Etot) return;
  int s, d;
  if (e < E) { s = src[e]; d = dst[e]; } else { s = d = e - E; }
  int pos = atomicAdd(&cursor[d], 1);
  csr[pos] = s;
}

// ------- layer-1 softmax-aggregation: out[d] = (sum ex*h1[s])/(sum ex) + b --
// One wave per dst node; lane = channel within head (64 ch x 3 heads).
__global__ __launch_bounds__(256) void agg1_kernel(const float* __restrict__ h1,
    const float* __restrict__ a1s, const float* __restrict__ a1d,
    const int* __restrict__ off, const int* __restrict__ csr,
    const float* __restrict__ b1, float* __restrict__ out, int n) {
  int wid = (blockIdx.x * 256 + threadIdx.x) >> 6;
  int lane = threadIdx.x & 63;
  if (wid >= n) return;
  float ad0 = a1d[wid * 3 + 0], ad1 = a1d[wid * 3 + 1], ad2 = a1d[wid * 3 + 2];
  int start = off[wid], end = off[wid + 1];
  float acc0 = 0.f, acc1 = 0.f, acc2 = 0.f;
  float den0 = 0.f, den1 = 0.f, den2 = 0.f;
  for (int base = start; base < end; base += 64) {
    int cnt = min(end - base, 64);
    int sv = (lane < cnt) ? csr[base + lane] : 0;   // prefetch src ids
    for (int j = 0; j < cnt; j++) {
      int s = __shfl(sv, j, 64);
      float e0 = LRELU(a1s[s * 3 + 0] + ad0);
      float e1 = LRELU(a1s[s * 3 + 1] + ad1);
      float e2 = LRELU(a1s[s * 3 + 2] + ad2);
      float x0 = __expf(e0), x1 = __expf(e1), x2 = __expf(e2);
      den0 += x0; den1 += x1; den2 += x2;
      const float* hp = h1 + (size_t)s * 192;
      acc0 = fmaf(x0, hp[lane],       acc0);
      acc1 = fmaf(x1, hp[64 + lane],  acc1);
      acc2 = fmaf(x2, hp[128 + lane], acc2);
    }
  }
  size_t o = (size_t)wid * 192;
  out[o + lane]        = acc0 / den0 + b1[lane];
  out[o + 64 + lane]   = acc1 / den1 + b1[64 + lane];
  out[o + 128 + lane]  = acc2 / den2 + b1[128 + lane];
}

// --- layer-2 GEMM [N,64]@[64,6] fused with a2_src/a2_dst; wave per node -----
__global__ __launch_bounds__(256) void gemm2_a2(const float* __restrict__ hfc,
    const float* __restrict__ W2, const float* __restrict__ as2,
    const float* __restrict__ ad2, float* __restrict__ h2,
    float* __restrict__ a2s, float* __restrict__ a2d, int n) {
  int wid = (blockIdx.x * 256 + threadIdx.x) >> 6;
  int lane = threadIdx.x & 63;
  if (wid >= n) return;
  float hv = hfc[(size_t)wid * 64 + lane];
  float o[6];
  #pragma unroll
  for (int j = 0; j < 6; j++) o[j] = wave_reduce(hv * W2[lane * 6 + j]);
  if (lane < 6) h2[(size_t)wid * 6 + lane] = o[lane];
  if (lane == 0) {
    #pragma unroll
    for (int h = 0; h < 3; h++) {
      a2s[wid * 3 + h] = o[h*2] * as2[h*2] + o[h*2+1] * as2[h*2+1];
      a2d[wid * 3 + h] = o[h*2] * ad2[h*2] + o[h*2+1] * ad2[h*2+1];
    }
  }
}

// --- layer-2 aggregation + head mean + bias + 2-way softmax; thread/node ----
__global__ void agg2_kernel(const float* __restrict__ h2, const float* __restrict__ a2s,
    const float* __restrict__ a2d, const int* __restrict__ off,
    const int* __restrict__ csr, const float* __restrict__ b2,
    float* __restrict__ outp, int n) {
  int d = blockIdx.x * 256 + threadIdx.x;
  if (d >= n) return;
  float ad0 = a2d[d*3], ad1 = a2d[d*3+1], ad2v = a2d[d*3+2];
  float den0 = 0.f, den1 = 0.f, den2 = 0.f;
  float a00 = 0.f, a01 = 0.f, a10 = 0.f, a11 = 0.f, a20 = 0.f, a21 = 0.f;
  int end = off[d + 1];
  for (int j = off[d]; j < end; j++) {
    int s = csr[j];
    float x0 = __expf(LRELU(a2s[s*3]     + ad0));
    float x1 = __expf(LRELU(a2s[s*3 + 1] + ad1));
    float x2 = __expf(LRELU(a2s[s*3 + 2] + ad2v));
    den0 += x0; den1 += x1; den2 += x2;
    const float* hp = h2 + (size_t)s * 6;
    a00 = fmaf(x0, hp[0], a00); a01 = fmaf(x0, hp[1], a01);
    a10 = fmaf(x1, hp[2], a10); a11 = fmaf(x1, hp[3], a11);
    a20 = fmaf(x2, hp[4], a20); a21 = fmaf(x2, hp[5], a21);
  }
  float l0 = (a00/den0 + a10/den1 + a20/den2) * (1.f/3.f) + b2[0];
  float l1 = (a01/den0 + a11/den1 + a21/den2) * (1.f/3.f) + b2[1];
  float m = fmaxf(l0, l1);
  float e0 = __expf(l0 - m), e1 = __expf(l1 - m);
  float inv = 1.f / (e0 + e1);
  outp[(size_t)d * 2]     = e0 * inv;
  outp[(size_t)d * 2 + 1] = e1 * inv;
}

extern "C" void kernel_launch(void* const* d_in, const int* in_sizes, int n_in,
                              void* d_out, int out_size, void* d_ws, size_t ws_size,
                              hipStream_t stream) {
  const float* x   = (const float*)d_in[0];
  const int*   ei  = (const int*)d_in[1];
  const float* W1  = (const float*)d_in[2];
  const float* as1 = (const float*)d_in[3];
  const float* ad1 = (const float*)d_in[4];
  const float* b1  = (const float*)d_in[5];
  const float* fcW = (const float*)d_in[6];
  const float* fcb = (const float*)d_in[7];
  const float* W2  = (const float*)d_in[8];
  const float* as2 = (const float*)d_in[9];
  const float* ad2 = (const float*)d_in[10];
  const float* b2  = (const float*)d_in[11];
  float* outp = (float*)d_out;

  const int Nn   = in_sizes[0] / 128;
  const int E    = in_sizes[1] / 2;
  const int Etot = E + Nn;
  const int* esrc = ei;
  const int* edst = ei + E;

  char* p = (char*)d_ws;
  auto alloc = [&](size_t bytes) {
    char* q = p; p += (bytes + 15) & ~(size_t)15; return q;
  };
  float* h1    = (float*)alloc((size_t)Nn * 192 * 4);  // later reused as hfc
  float* out1  = (float*)alloc((size_t)Nn * 192 * 4);  // later reused as h2/a2
  float* a1s   = (float*)alloc((size_t)Nn * 3 * 4);
  float* a1d   = (float*)alloc((size_t)Nn * 3 * 4);
  int* deg     = (int*)alloc((size_t)Nn * 4);
  int* off     = (int*)alloc((size_t)(Nn + 1) * 4);
  int* cursor  = (int*)alloc((size_t)Nn * 4);
  int* texcl   = (int*)alloc((size_t)Nn * 4);
  int* bsum    = (int*)alloc(512 * 4);
  int* boff    = (int*)alloc(512 * 4);
  int* csr     = (int*)alloc((size_t)Etot * 4);
  float* hfc = h1;                       // [N,64] fits in h1's space
  float* h2  = out1;                     // [N,6]
  float* a2s = out1 + (size_t)Nn * 6;    // [N,3]
  float* a2d = a2s + (size_t)Nn * 3;     // [N,3]

  hipMemsetAsync(deg, 0, (size_t)Nn * 4, stream);

  // 1. h1 = x @ W1   [N,192]
  dim3 g1((Nn + 63) / 64, 3);
  gemm64<false, false><<<g1, 256, 0, stream>>>(x, W1, nullptr, h1, Nn, 192, 128);

  // 2. attention coefficients per node
  int nb4 = (Nn + 3) / 4;
  a1_kernel<<<nb4, 256, 0, stream>>>(h1, as1, ad1, a1s, a1d, Nn);

  // 3. CSR build (dst-sorted src list), shared by both layers
  int eb = (Etot + 255) / 256;
  int sb = (Nn + 255) / 256;
  edge_count<<<eb, 256, 0, stream>>>(edst, deg, E, Etot);
  scan1<<<sb, 256, 0, stream>>>(deg, texcl, bsum, Nn);
  scan2<<<1, 512, 0, stream>>>(bsum, boff, sb);
  scan3<<<sb, 256, 0, stream>>>(texcl, boff, off, cursor, Nn, Etot);
  edge_fill<<<eb, 256, 0, stream>>>(esrc, edst, cursor, csr, E, Etot);

  // 4. layer-1 softmax aggregation (+bias)
  agg1_kernel<<<nb4, 256, 0, stream>>>(h1, a1s, a1d, off, csr, b1, out1, Nn);

  // 5. hfc = relu(out1 @ fcW + fcb)   [N,64]  (writes into h1's buffer)
  dim3 g2((Nn + 63) / 64, 1);
  gemm64<true, true><<<g2, 256, 0, stream>>>(out1, fcW, fcb, hfc, Nn, 64, 192);

  // 6. h2 = hfc @ W2 fused with a2 coefficients
  gemm2_a2<<<nb4, 256, 0, stream>>>(hfc, W2, as2, ad2, h2, a2s, a2d, Nn);

  // 7. layer-2 aggregation + head mean + bias + softmax -> output
  agg2_kernel<<<sb, 256, 0, stream>>>(h2, a2s, a2d, off, csr, b2, outp, Nn);
}

// Round 2
// 673.298 us; speedup vs baseline: 1.0517x; 1.0517x over previous
//
#include <hip/hip_runtime.h>
#include <cstdint>
#include <cstddef>

typedef unsigned short ushort_t;
typedef unsigned short ushort8 __attribute__((ext_vector_type(8)));

#define LRELU(x) ((x) > 0.f ? (x) : 0.2f*(x))

__device__ __forceinline__ float bf2f(ushort_t u) {
  return __uint_as_float(((unsigned int)u) << 16);
}
__device__ __forceinline__ ushort_t f2bf(float f) {
  unsigned int b = __float_as_uint(f);
  b += 0x7fffu + ((b >> 16) & 1u);
  return (ushort_t)(b >> 16);
}

__device__ __forceinline__ float wave_reduce(float v) {
  #pragma unroll
  for (int m = 32; m > 0; m >>= 1) v += __shfl_xor(v, m, 64);
  return v;
}

// ---- 256x64-tile f32 GEMM, 8x8 micro-tile. C[M,N] = A[M,K] @ B[K,N] --------
// blockIdx.y = 64-col block (== head for gemm1). Optional fused epilogue:
//  BF16OUT: store C as bf16;  ATT: also emit per-row dot(C_row, atts/attd)
//  (valid because one block covers the full 64-col head).
template<bool BF16OUT, bool ATT, bool RELU, bool BIAS>
__global__ __launch_bounds__(256) void gemm256(const float* __restrict__ A,
    const float* __restrict__ Bm, const float* __restrict__ bias,
    void* __restrict__ Cout, float* __restrict__ a_s, float* __restrict__ a_d,
    const float* __restrict__ atts, const float* __restrict__ attd,
    int M, int N, int K) {
  __shared__ float As[32][260];   // [k][row], pad 260: f4-aligned, 2-way-only banks
  __shared__ float Bs[32][68];    // [k][col]
  const int tid = threadIdx.x;
  const int tx = tid & 7;         // col group (8 cols)
  const int ty = tid >> 3;        // row group (8 rows), 0..31
  const int r0 = blockIdx.x * 256;
  const int c0 = blockIdx.y * 64;
  float acc[8][8] = {};
  for (int k0 = 0; k0 < K; k0 += 32) {
    #pragma unroll
    for (int i = 0; i < 8; i++) {              // A tile: 2048 float4
      int f = tid + i * 256;
      int row = f >> 3, k4 = (f & 7) << 2;
      float4 v = make_float4(0.f, 0.f, 0.f, 0.f);
      int gr = r0 + row;
      if (gr < M) v = *(const float4*)(A + (size_t)gr * K + k0 + k4);
      As[k4 + 0][row] = v.x; As[k4 + 1][row] = v.y;
      As[k4 + 2][row] = v.z; As[k4 + 3][row] = v.w;
    }
    #pragma unroll
    for (int i = 0; i < 2; i++) {              // B tile: 512 float4
      int f = tid + i * 256;
      int kr = f >> 4, c4 = (f & 15) << 2;
      *(float4*)&Bs[kr][c4] = *(const float4*)(Bm + (size_t)(k0 + kr) * N + c0 + c4);
    }
    __syncthreads();
    #pragma unroll
    for (int kk = 0; kk < 32; kk++) {
      float a[8], b[8];
      *(float4*)&a[0] = *(const float4*)&As[kk][ty * 8];
      *(float4*)&a[4] = *(const float4*)&As[kk][ty * 8 + 4];
      *(float4*)&b[0] = *(const float4*)&Bs[kk][tx * 8];
      *(float4*)&b[4] = *(const float4*)&Bs[kk][tx * 8 + 4];
      #pragma unroll
      for (int i = 0; i < 8; i++)
        #pragma unroll
        for (int j = 0; j < 8; j++)
          acc[i][j] = fmaf(a[i], b[j], acc[i][j]);
    }
    __syncthreads();
  }
  float vs[8], vd[8], bb[8];
  if (ATT) {
    #pragma unroll
    for (int j = 0; j < 8; j++) {
      vs[j] = atts[c0 + tx * 8 + j];
      vd[j] = attd[c0 + tx * 8 + j];
    }
  }
  if (BIAS) {
    #pragma unroll
    for (int j = 0; j < 8; j++) bb[j] = bias[c0 + tx * 8 + j];
  }
  #pragma unroll
  for (int i = 0; i < 8; i++) {
    int r = r0 + ty * 8 + i;
    bool ok = r < M;
    if (ATT) {   // per-row attention dots (f32, pre-rounding); reduce over tx
      float ps = 0.f, pd = 0.f;
      #pragma unroll
      for (int j = 0; j < 8; j++) {
        ps = fmaf(acc[i][j], vs[j], ps);
        pd = fmaf(acc[i][j], vd[j], pd);
      }
      #pragma unroll
      for (int m = 1; m < 8; m <<= 1) {   // xor within tx-group: same r per group
        ps += __shfl_xor(ps, m, 64);
        pd += __shfl_xor(pd, m, 64);
      }
      if (ok && tx == 0) {
        a_s[r * 3 + blockIdx.y] = ps;
        a_d[r * 3 + blockIdx.y] = pd;
      }
    }
    if (!ok) continue;
    if (BF16OUT) {
      ushort8 u;
      #pragma unroll
      for (int j = 0; j < 8; j++) u[j] = f2bf(acc[i][j]);
      *(ushort8*)((ushort_t*)Cout + (size_t)r * N + c0 + tx * 8) = u;
    } else {
      float o[8];
      #pragma unroll
      for (int j = 0; j < 8; j++) {
        o[j] = acc[i][j];
        if (BIAS) o[j] += bb[j];
        if (RELU) o[j] = fmaxf(o[j], 0.f);
      }
      float* cp = (float*)Cout + (size_t)r * N + c0 + tx * 8;
      *(float4*)cp = make_float4(o[0], o[1], o[2], o[3]);
      *(float4*)(cp + 4) = make_float4(o[4], o[5], o[6], o[7]);
    }
  }
}

// ---------------- CSR build (shared by both GAT layers) ---------------------
__global__ void edge_count(const int* __restrict__ dst, int* __restrict__ deg,
                           int E, int Etot) {
  int e = blockIdx.x * 256 + threadIdx.x;
  if (e >= Etot) return;
  int d = (e < E) ? dst[e] : (e - E);
  atomicAdd(&deg[d], 1);
}

__global__ void scan1(const int* __restrict__ deg, int* __restrict__ excl,
                      int* __restrict__ bsum, int n) {
  __shared__ int sh[256];
  int t = threadIdx.x;
  int idx = blockIdx.x * 256 + t;
  int v = (idx < n) ? deg[idx] : 0;
  sh[t] = v;
  __syncthreads();
  for (int ofs = 1; ofs < 256; ofs <<= 1) {
    int add = (t >= ofs) ? sh[t - ofs] : 0;
    __syncthreads();
    sh[t] += add;
    __syncthreads();
  }
  if (idx < n) excl[idx] = sh[t] - v;
  if (t == 255) bsum[blockIdx.x] = sh[255];
}

__global__ void scan2(const int* __restrict__ bsum, int* __restrict__ boff, int nb) {
  __shared__ int sh[512];
  int t = threadIdx.x;
  int v = (t < nb) ? bsum[t] : 0;
  sh[t] = v;
  __syncthreads();
  for (int ofs = 1; ofs < 512; ofs <<= 1) {
    int add = (t >= ofs) ? sh[t - ofs] : 0;
    __syncthreads();
    sh[t] += add;
    __syncthreads();
  }
  if (t < nb) boff[t] = sh[t] - v;
}

__global__ void scan3(const int* __restrict__ excl, const int* __restrict__ boff,
                      int* __restrict__ off, int* __restrict__ cursor, int n, int etot) {
  int idx = blockIdx.x * 256 + threadIdx.x;
  if (idx < n) {
    int o = excl[idx] + boff[blockIdx.x];
    off[idx] = o;
    cursor[idx] = o;
  }
  if (idx == 0) off[n] = etot;
}

__global__ void edge_fill(const int* __restrict__ src, const int* __restrict__ dst,
                          int* __restrict__ cursor, int* __restrict__ csr,
                          int E, int Etot) {
  int e = blockIdx.x * 256 + threadIdx.x;
  if (e >= Etot) return;
  int s, d;
  if (e < E) { s = src[e]; d = dst[e]; } else { s = d = e - E; }
  int pos = atomicAdd(&cursor[d], 1);
  csr[pos] = s;
}

// ------- layer-1 softmax-aggregation: out[d] = (sum ex*h1[s])/(sum ex) + b --
// One wave per dst node; lane = channel. h1 gathered as bf16 (halved bytes).
__global__ __launch_bounds__(256) void agg1_kernel(const ushort_t* __restrict__ h1,
    const float* __restrict__ a1s, const float* __restrict__ a1d,
    const int* __restrict__ off, const int* __restrict__ csr,
    const float* __restrict__ b1, float* __restrict__ out, int n) {
  int wid = (blockIdx.x * 256 + threadIdx.x) >> 6;
  int lane = threadIdx.x & 63;
  if (wid >= n) return;
  float ad0 = a1d[wid * 3 + 0], ad1 = a1d[wid * 3 + 1], ad2 = a1d[wid * 3 + 2];
  int start = off[wid], end = off[wid + 1];
  float acc0 = 0.f, acc1 = 0.f, acc2 = 0.f;
  float den0 = 0.f, den1 = 0.f, den2 = 0.f;
  for (int base = start; base < end; base += 64) {
    int cnt = min(end - base, 64);
    int sv = (lane < cnt) ? csr[base + lane] : 0;   // prefetch src ids
    for (int j = 0; j < cnt; j++) {
      int s = __shfl(sv, j, 64);
      float e0 = LRELU(a1s[s * 3 + 0] + ad0);
      float e1 = LRELU(a1s[s * 3 + 1] + ad1);
      float e2 = LRELU(a1s[s * 3 + 2] + ad2);
      float x0 = __expf(e0), x1 = __expf(e1), x2 = __expf(e2);
      den0 += x0; den1 += x1; den2 += x2;
      const ushort_t* hp = h1 + (size_t)s * 192;
      acc0 = fmaf(x0, bf2f(hp[lane]),       acc0);
      acc1 = fmaf(x1, bf2f(hp[64 + lane]),  acc1);
      acc2 = fmaf(x2, bf2f(hp[128 + lane]), acc2);
    }
  }
  size_t o = (size_t)wid * 192;
  out[o + lane]       = acc0 / den0 + b1[lane];
  out[o + 64 + lane]  = acc1 / den1 + b1[64 + lane];
  out[o + 128 + lane] = acc2 / den2 + b1[128 + lane];
}

// --- layer-2 GEMM [N,64]@[64,6] fused with a2_src/a2_dst; wave per node -----
__global__ __launch_bounds__(256) void gemm2_a2(const float* __restrict__ hfc,
    const float* __restrict__ W2, const float* __restrict__ as2,
    const float* __restrict__ ad2, float* __restrict__ h2,
    float* __restrict__ a2s, float* __restrict__ a2d, int n) {
  int wid = (blockIdx.x * 256 + threadIdx.x) >> 6;
  int lane = threadIdx.x & 63;
  if (wid >= n) return;
  float hv = hfc[(size_t)wid * 64 + lane];
  float o[6];
  #pragma unroll
  for (int j = 0; j < 6; j++) o[j] = wave_reduce(hv * W2[lane * 6 + j]);
  if (lane < 6) h2[(size_t)wid * 6 + lane] = o[lane];
  if (lane == 0) {
    #pragma unroll
    for (int h = 0; h < 3; h++) {
      a2s[wid * 3 + h] = o[h*2] * as2[h*2] + o[h*2+1] * as2[h*2+1];
      a2d[wid * 3 + h] = o[h*2] * ad2[h*2] + o[h*2+1] * ad2[h*2+1];
    }
  }
}

// --- layer-2 aggregation + head mean + bias + 2-way softmax -----------------
// 8 lanes per node (edge-parallel), 8 nodes per wave; shfl-reduce 9 partials.
__global__ __launch_bounds__(256) void agg2_kernel(const float* __restrict__ h2,
    const float* __restrict__ a2s, const float* __restrict__ a2d,
    const int* __restrict__ off, const int* __restrict__ csr,
    const float* __restrict__ b2, float* __restrict__ outp, int n) {
  int wave = (blockIdx.x * 256 + threadIdx.x) >> 6;
  int lane = threadIdx.x & 63;
  int g = lane >> 3, sub = lane & 7;
  int d = wave * 8 + g;
  bool valid = d < n;
  float ad0 = 0.f, ad1 = 0.f, ad2v = 0.f;
  int start = 0, end = 0;
  if (valid) {
    ad0 = a2d[d*3]; ad1 = a2d[d*3+1]; ad2v = a2d[d*3+2];
    start = off[d]; end = off[d + 1];
  }
  float den0 = 0.f, den1 = 0.f, den2 = 0.f;
  float a00 = 0.f, a01 = 0.f, a10 = 0.f, a11 = 0.f, a20 = 0.f, a21 = 0.f;
  for (int j = start + sub; j < end; j += 8) {
    int s = csr[j];
    float x0 = __expf(LRELU(a2s[s*3]     + ad0));
    float x1 = __expf(LRELU(a2s[s*3 + 1] + ad1));
    float x2 = __expf(LRELU(a2s[s*3 + 2] + ad2v));
    den0 += x0; den1 += x1; den2 += x2;
    const float* hp = h2 + (size_t)s * 6;
    a00 = fmaf(x0, hp[0], a00); a01 = fmaf(x0, hp[1], a01);
    a10 = fmaf(x1, hp[2], a10); a11 = fmaf(x1, hp[3], a11);
    a20 = fmaf(x2, hp[4], a20); a21 = fmaf(x2, hp[5], a21);
  }
  #pragma unroll
  for (int m = 1; m < 8; m <<= 1) {   // reduce within 8-lane group
    den0 += __shfl_xor(den0, m, 64); den1 += __shfl_xor(den1, m, 64);
    den2 += __shfl_xor(den2, m, 64);
    a00 += __shfl_xor(a00, m, 64); a01 += __shfl_xor(a01, m, 64);
    a10 += __shfl_xor(a10, m, 64); a11 += __shfl_xor(a11, m, 64);
    a20 += __shfl_xor(a20, m, 64); a21 += __shfl_xor(a21, m, 64);
  }
  if (valid && sub == 0) {
    float l0 = (a00/den0 + a10/den1 + a20/den2) * (1.f/3.f) + b2[0];
    float l1 = (a01/den0 + a11/den1 + a21/den2) * (1.f/3.f) + b2[1];
    float m = fmaxf(l0, l1);
    float e0 = __expf(l0 - m), e1 = __expf(l1 - m);
    float inv = 1.f / (e0 + e1);
    *(float2*)(outp + (size_t)d * 2) = make_float2(e0 * inv, e1 * inv);
  }
}

extern "C" void kernel_launch(void* const* d_in, const int* in_sizes, int n_in,
                              void* d_out, int out_size, void* d_ws, size_t ws_size,
                              hipStream_t stream) {
  const float* x   = (const float*)d_in[0];
  const int*   ei  = (const int*)d_in[1];
  const float* W1  = (const float*)d_in[2];
  const float* as1 = (const float*)d_in[3];
  const float* ad1 = (const float*)d_in[4];
  const float* b1  = (const float*)d_in[5];
  const float* fcW = (const float*)d_in[6];
  const float* fcb = (const float*)d_in[7];
  const float* W2  = (const float*)d_in[8];
  const float* as2 = (const float*)d_in[9];
  const float* ad2 = (const float*)d_in[10];
  const float* b2  = (const float*)d_in[11];
  float* outp = (float*)d_out;

  const int Nn   = in_sizes[0] / 128;
  const int E    = in_sizes[1] / 2;
  const int Etot = E + Nn;
  const int* esrc = ei;
  const int* edst = ei + E;

  char* p = (char*)d_ws;
  auto alloc = [&](size_t bytes) {
    char* q = p; p += (bytes + 255) & ~(size_t)255; return q;
  };
  ushort_t* h1bf = (ushort_t*)alloc((size_t)Nn * 192 * 2);  // later reused as hfc
  float* out1  = (float*)alloc((size_t)Nn * 192 * 4);       // later reused as h2/a2
  float* a1s   = (float*)alloc((size_t)Nn * 3 * 4);
  float* a1d   = (float*)alloc((size_t)Nn * 3 * 4);
  int* deg     = (int*)alloc((size_t)Nn * 4);
  int* off     = (int*)alloc((size_t)(Nn + 1) * 4);
  int* cursor  = (int*)alloc((size_t)Nn * 4);
  int* texcl   = (int*)alloc((size_t)Nn * 4);
  int* bsum    = (int*)alloc(512 * 4);
  int* boff    = (int*)alloc(512 * 4);
  int* csr     = (int*)alloc((size_t)Etot * 4);
  float* hfc = (float*)h1bf;             // [N,64] f32 fits in h1bf's 38 MB
  float* h2  = out1;                     // [N,6]
  float* a2s = out1 + (size_t)Nn * 6;    // [N,3]
  float* a2d = a2s + (size_t)Nn * 3;     // [N,3]

  hipMemsetAsync(deg, 0, (size_t)Nn * 4, stream);

  const int mb = (Nn + 255) / 256;       // 391 row-blocks
  const int nb4 = (Nn + 3) / 4;
  const int eb = (Etot + 255) / 256;
  const int sb = (Nn + 255) / 256;

  // 1. h1(bf16) = x @ W1, fused: a1s/a1d per-row attention dots (f32)
  gemm256<true, true, false, false><<<dim3(mb, 3), 256, 0, stream>>>(
      x, W1, nullptr, h1bf, a1s, a1d, as1, ad1, Nn, 192, 128);

  // 2. CSR build (dst-sorted src list), shared by both layers
  edge_count<<<eb, 256, 0, stream>>>(edst, deg, E, Etot);
  scan1<<<sb, 256, 0, stream>>>(deg, texcl, bsum, Nn);
  scan2<<<1, 512, 0, stream>>>(bsum, boff, sb);
  scan3<<<sb, 256, 0, stream>>>(texcl, boff, off, cursor, Nn, Etot);
  edge_fill<<<eb, 256, 0, stream>>>(esrc, edst, cursor, csr, E, Etot);

  // 3. layer-1 softmax aggregation (+bias)
  agg1_kernel<<<nb4, 256, 0, stream>>>(h1bf, a1s, a1d, off, csr, b1, out1, Nn);

  // 4. hfc = relu(out1 @ fcW + fcb)   [N,64]
  gemm256<false, false, true, true><<<dim3(mb, 1), 256, 0, stream>>>(
      out1, fcW, fcb, hfc, nullptr, nullptr, nullptr, nullptr, Nn, 64, 192);

  // 5. h2 = hfc @ W2 fused with a2 coefficients
  gemm2_a2<<<nb4, 256, 0, stream>>>(hfc, W2, as2, ad2, h2, a2s, a2d, Nn);

  // 6. layer-2 aggregation + head mean + bias + softmax -> output
  agg2_kernel<<<(Nn/8 + 3) / 4 + 1, 256, 0, stream>>>(h2, a2s, a2d, off, csr, b2, outp, Nn);
}

// Round 5
// 640.324 us; speedup vs baseline: 1.1059x; 1.0515x over previous
//
#include <hip/hip_runtime.h>
#include <cstdint>
#include <cstddef>

typedef unsigned short ushort_t;
typedef unsigned short ushort8 __attribute__((ext_vector_type(8)));

#define LRELU(x) ((x) > 0.f ? (x) : 0.2f*(x))

__device__ __forceinline__ float bf2f(ushort_t u) {
  return __uint_as_float(((unsigned int)u) << 16);
}
__device__ __forceinline__ ushort_t f2bf(float f) {
  unsigned int b = __float_as_uint(f);
  b += 0x7fffu + ((b >> 16) & 1u);
  return (ushort_t)(b >> 16);
}
__device__ __forceinline__ float readlane_f(float v, int l) {
  return __uint_as_float(__builtin_amdgcn_readlane(__float_as_uint(v), l));
}

__device__ __forceinline__ float wave_reduce(float v) {
  #pragma unroll
  for (int m = 32; m > 0; m >>= 1) v += __shfl_xor(v, m, 64);
  return v;
}

// ---- 256x64-tile f32 GEMM, 8x8 micro-tile. C[M,N] = A[M,K] @ B[K,N] --------
// blockIdx.y = 64-col block (== head for gemm1). Optional fused epilogue:
//  BF16OUT: store C as bf16;  ATT: also emit per-row dot(C_row, atts/attd)
//  (valid because one block covers the full 64-col head).
template<bool BF16OUT, bool ATT, bool RELU, bool BIAS>
__global__ __launch_bounds__(256) void gemm256(const float* __restrict__ A,
    const float* __restrict__ Bm, const float* __restrict__ bias,
    void* __restrict__ Cout, float* __restrict__ a_s, float* __restrict__ a_d,
    const float* __restrict__ atts, const float* __restrict__ attd,
    int M, int N, int K) {
  __shared__ float As[32][260];   // [k][row], pad 260: f4-aligned, 2-way-only banks
  __shared__ float Bs[32][68];    // [k][col]
  const int tid = threadIdx.x;
  const int tx = tid & 7;         // col group (8 cols)
  const int ty = tid >> 3;        // row group (8 rows), 0..31
  const int r0 = blockIdx.x * 256;
  const int c0 = blockIdx.y * 64;
  float acc[8][8] = {};
  for (int k0 = 0; k0 < K; k0 += 32) {
    #pragma unroll
    for (int i = 0; i < 8; i++) {              // A tile: 2048 float4
      int f = tid + i * 256;
      int row = f >> 3, k4 = (f & 7) << 2;
      float4 v = make_float4(0.f, 0.f, 0.f, 0.f);
      int gr = r0 + row;
      if (gr < M) v = *(const float4*)(A + (size_t)gr * K + k0 + k4);
      As[k4 + 0][row] = v.x; As[k4 + 1][row] = v.y;
      As[k4 + 2][row] = v.z; As[k4 + 3][row] = v.w;
    }
    #pragma unroll
    for (int i = 0; i < 2; i++) {              // B tile: 512 float4
      int f = tid + i * 256;
      int kr = f >> 4, c4 = (f & 15) << 2;
      *(float4*)&Bs[kr][c4] = *(const float4*)(Bm + (size_t)(k0 + kr) * N + c0 + c4);
    }
    __syncthreads();
    #pragma unroll
    for (int kk = 0; kk < 32; kk++) {
      float a[8], b[8];
      *(float4*)&a[0] = *(const float4*)&As[kk][ty * 8];
      *(float4*)&a[4] = *(const float4*)&As[kk][ty * 8 + 4];
      *(float4*)&b[0] = *(const float4*)&Bs[kk][tx * 8];
      *(float4*)&b[4] = *(const float4*)&Bs[kk][tx * 8 + 4];
      #pragma unroll
      for (int i = 0; i < 8; i++)
        #pragma unroll
        for (int j = 0; j < 8; j++)
          acc[i][j] = fmaf(a[i], b[j], acc[i][j]);
    }
    __syncthreads();
  }
  float vs[8], vd[8], bb[8];
  if (ATT) {
    #pragma unroll
    for (int j = 0; j < 8; j++) {
      vs[j] = atts[c0 + tx * 8 + j];
      vd[j] = attd[c0 + tx * 8 + j];
    }
  }
  if (BIAS) {
    #pragma unroll
    for (int j = 0; j < 8; j++) bb[j] = bias[c0 + tx * 8 + j];
  }
  #pragma unroll
  for (int i = 0; i < 8; i++) {
    int r = r0 + ty * 8 + i;
    bool ok = r < M;
    if (ATT) {   // per-row attention dots (f32, pre-rounding); reduce over tx
      float ps = 0.f, pd = 0.f;
      #pragma unroll
      for (int j = 0; j < 8; j++) {
        ps = fmaf(acc[i][j], vs[j], ps);
        pd = fmaf(acc[i][j], vd[j], pd);
      }
      #pragma unroll
      for (int m = 1; m < 8; m <<= 1) {   // xor within tx-group: same r per group
        ps += __shfl_xor(ps, m, 64);
        pd += __shfl_xor(pd, m, 64);
      }
      if (ok && tx == 0) {
        a_s[r * 3 + blockIdx.y] = ps;
        a_d[r * 3 + blockIdx.y] = pd;
      }
    }
    if (!ok) continue;
    if (BF16OUT) {
      ushort8 u;
      #pragma unroll
      for (int j = 0; j < 8; j++) u[j] = f2bf(acc[i][j]);
      *(ushort8*)((ushort_t*)Cout + (size_t)r * N + c0 + tx * 8) = u;
    } else {
      float o[8];
      #pragma unroll
      for (int j = 0; j < 8; j++) {
        o[j] = acc[i][j];
        if (BIAS) o[j] += bb[j];
        if (RELU) o[j] = fmaxf(o[j], 0.f);
      }
      float* cp = (float*)Cout + (size_t)r * N + c0 + tx * 8;
      *(float4*)cp = make_float4(o[0], o[1], o[2], o[3]);
      *(float4*)(cp + 4) = make_float4(o[4], o[5], o[6], o[7]);
    }
  }
}

// ---------------- CSR build (shared by both GAT layers) ---------------------
__global__ void edge_count(const int* __restrict__ dst, int* __restrict__ deg,
                           int E, int Etot) {
  int e = blockIdx.x * 256 + threadIdx.x;
  if (e >= Etot) return;
  int d = (e < E) ? dst[e] : (e - E);
  atomicAdd(&deg[d], 1);
}

__global__ void scan1(const int* __restrict__ deg, int* __restrict__ excl,
                      int* __restrict__ bsum, int n) {
  __shared__ int sh[256];
  int t = threadIdx.x;
  int idx = blockIdx.x * 256 + t;
  int v = (idx < n) ? deg[idx] : 0;
  sh[t] = v;
  __syncthreads();
  for (int ofs = 1; ofs < 256; ofs <<= 1) {
    int add = (t >= ofs) ? sh[t - ofs] : 0;
    __syncthreads();
    sh[t] += add;
    __syncthreads();
  }
  if (idx < n) excl[idx] = sh[t] - v;
  if (t == 255) bsum[blockIdx.x] = sh[255];
}

__global__ void scan2(const int* __restrict__ bsum, int* __restrict__ boff, int nb) {
  __shared__ int sh[512];
  int t = threadIdx.x;
  int v = (t < nb) ? bsum[t] : 0;
  sh[t] = v;
  __syncthreads();
  for (int ofs = 1; ofs < 512; ofs <<= 1) {
    int add = (t >= ofs) ? sh[t - ofs] : 0;
    __syncthreads();
    sh[t] += add;
    __syncthreads();
  }
  if (t < nb) boff[t] = sh[t] - v;
}

__global__ void scan3(const int* __restrict__ excl, const int* __restrict__ boff,
                      int* __restrict__ off, int* __restrict__ cursor, int n, int etot) {
  int idx = blockIdx.x * 256 + threadIdx.x;
  if (idx < n) {
    int o = excl[idx] + boff[blockIdx.x];
    off[idx] = o;
    cursor[idx] = o;
  }
  if (idx == 0) off[n] = etot;
}

__global__ void edge_fill(const int* __restrict__ src, const int* __restrict__ dst,
                          int* __restrict__ cursor, int* __restrict__ csr,
                          int E, int Etot) {
  int e = blockIdx.x * 256 + threadIdx.x;
  if (e >= Etot) return;
  int s, d;
  if (e < E) { s = src[e]; d = dst[e]; } else { s = d = e - E; }
  int pos = atomicAdd(&cursor[d], 1);
  csr[pos] = s;
}

// ------- layer-1 softmax-aggregation: out[d] = (sum ex*h1[s])/(sum ex) + b --
// One wave per dst node; lane = channel. h1 gathered as bf16.
// Exp/LeakyReLU/a1s-gather hoisted to the lane-parallel prefetch phase;
// inner loop broadcasts via readlane (SALU) -> SGPR base addresses.
__global__ __launch_bounds__(256) void agg1_kernel(const ushort_t* __restrict__ h1,
    const float* __restrict__ a1s, const float* __restrict__ a1d,
    const int* __restrict__ off, const int* __restrict__ csr,
    const float* __restrict__ b1, float* __restrict__ out, int n) {
  int wid = (blockIdx.x * 256 + threadIdx.x) >> 6;
  int lane = threadIdx.x & 63;
  if (wid >= n) return;
  float ad0 = a1d[wid * 3 + 0], ad1 = a1d[wid * 3 + 1], ad2 = a1d[wid * 3 + 2];
  int start = off[wid], end = off[wid + 1];
  float acc0 = 0.f, acc1 = 0.f, acc2 = 0.f;
  float den0 = 0.f, den1 = 0.f, den2 = 0.f;
  for (int base = start; base < end; base += 64) {
    int cnt = min(end - base, 64);
    int sv = 0;
    float px0 = 0.f, px1 = 0.f, px2 = 0.f;
    if (lane < cnt) {                       // lane-parallel per-edge coeffs
      sv = csr[base + lane];
      px0 = __expf(LRELU(a1s[sv * 3 + 0] + ad0));
      px1 = __expf(LRELU(a1s[sv * 3 + 1] + ad1));
      px2 = __expf(LRELU(a1s[sv * 3 + 2] + ad2));
      den0 += px0; den1 += px1; den2 += px2;
    }
    int j = 0;
    for (; j + 1 < cnt; j += 2) {           // unroll-2 for load ILP
      int sA = __builtin_amdgcn_readlane(sv, j);
      int sB = __builtin_amdgcn_readlane(sv, j + 1);
      float xA0 = readlane_f(px0, j), xA1 = readlane_f(px1, j), xA2 = readlane_f(px2, j);
      float xB0 = readlane_f(px0, j+1), xB1 = readlane_f(px1, j+1), xB2 = readlane_f(px2, j+1);
      const ushort_t* hA = h1 + (size_t)sA * 192;
      const ushort_t* hB = h1 + (size_t)sB * 192;
      float a0 = bf2f(hA[lane]), a1v = bf2f(hA[64 + lane]), a2v = bf2f(hA[128 + lane]);
      float b0 = bf2f(hB[lane]), b1v = bf2f(hB[64 + lane]), b2v = bf2f(hB[128 + lane]);
      acc0 = fmaf(xA0, a0, acc0); acc1 = fmaf(xA1, a1v, acc1); acc2 = fmaf(xA2, a2v, acc2);
      acc0 = fmaf(xB0, b0, acc0); acc1 = fmaf(xB1, b1v, acc1); acc2 = fmaf(xB2, b2v, acc2);
    }
    if (j < cnt) {                          // odd tail
      int sA = __builtin_amdgcn_readlane(sv, j);
      float xA0 = readlane_f(px0, j), xA1 = readlane_f(px1, j), xA2 = readlane_f(px2, j);
      const ushort_t* hA = h1 + (size_t)sA * 192;
      acc0 = fmaf(xA0, bf2f(hA[lane]),       acc0);
      acc1 = fmaf(xA1, bf2f(hA[64 + lane]),  acc1);
      acc2 = fmaf(xA2, bf2f(hA[128 + lane]), acc2);
    }
  }
  den0 = wave_reduce(den0); den1 = wave_reduce(den1); den2 = wave_reduce(den2);
  size_t o = (size_t)wid * 192;
  out[o + lane]       = acc0 / den0 + b1[lane];
  out[o + 64 + lane]  = acc1 / den1 + b1[64 + lane];
  out[o + 128 + lane] = acc2 / den2 + b1[128 + lane];
}

// --- layer-2 GEMM [N,64]@[64,6] + a2 coeffs -> packed 12-float rows ---------
// pk[d] = [h2(6), a2s(3), a2d(3)]; wave per node.
__global__ __launch_bounds__(256) void gemm2_pack(const float* __restrict__ hfc,
    const float* __restrict__ W2, const float* __restrict__ as2,
    const float* __restrict__ ad2, float* __restrict__ pk, int n) {
  int wid = (blockIdx.x * 256 + threadIdx.x) >> 6;
  int lane = threadIdx.x & 63;
  if (wid >= n) return;
  float hv = hfc[(size_t)wid * 64 + lane];
  float o[6];
  #pragma unroll
  for (int j = 0; j < 6; j++) o[j] = wave_reduce(hv * W2[lane * 6 + j]);
  if (lane == 0) {
    float* pp = pk + (size_t)wid * 12;
    *(float4*)pp = make_float4(o[0], o[1], o[2], o[3]);
    *(float4*)(pp + 4) = make_float4(o[4], o[5],
        o[0]*as2[0] + o[1]*as2[1], o[2]*as2[2] + o[3]*as2[3]);
    *(float4*)(pp + 8) = make_float4(o[4]*as2[4] + o[5]*as2[5],
        o[0]*ad2[0] + o[1]*ad2[1], o[2]*ad2[2] + o[3]*ad2[3],
        o[4]*ad2[4] + o[5]*ad2[5]);
  }
}

// --- layer-2 aggregation + head mean + bias + 2-way softmax -----------------
// 8 lanes per node (edge-parallel), 8 nodes per wave; packed 48B gather/edge.
__global__ __launch_bounds__(256) void agg2_kernel(const float* __restrict__ pk,
    const int* __restrict__ off, const int* __restrict__ csr,
    const float* __restrict__ b2, float* __restrict__ outp, int n) {
  int wave = (blockIdx.x * 256 + threadIdx.x) >> 6;
  int lane = threadIdx.x & 63;
  int g = lane >> 3, sub = lane & 7;
  int d = wave * 8 + g;
  bool valid = d < n;
  float ad0 = 0.f, ad1 = 0.f, ad2v = 0.f;
  int start = 0, end = 0;
  if (valid) {
    const float* pd = pk + (size_t)d * 12;
    ad0 = pd[9]; ad1 = pd[10]; ad2v = pd[11];
    start = off[d]; end = off[d + 1];
  }
  float den0 = 0.f, den1 = 0.f, den2 = 0.f;
  float a00 = 0.f, a01 = 0.f, a10 = 0.f, a11 = 0.f, a20 = 0.f, a21 = 0.f;
  for (int j = start + sub; j < end; j += 8) {
    int s = csr[j];
    const float* ps = pk + (size_t)s * 12;
    float4 A = *(const float4*)ps;        // h2[0..3]
    float4 B = *(const float4*)(ps + 4);  // h2[4], h2[5], a2s0, a2s1
    float  c = ps[8];                     // a2s2
    float x0 = __expf(LRELU(B.z + ad0));
    float x1 = __expf(LRELU(B.w + ad1));
    float x2 = __expf(LRELU(c   + ad2v));
    den0 += x0; den1 += x1; den2 += x2;
    a00 = fmaf(x0, A.x, a00); a01 = fmaf(x0, A.y, a01);
    a10 = fmaf(x1, A.z, a10); a11 = fmaf(x1, A.w, a11);
    a20 = fmaf(x2, B.x, a20); a21 = fmaf(x2, B.y, a21);
  }
  #pragma unroll
  for (int m = 1; m < 8; m <<= 1) {   // reduce within 8-lane group
    den0 += __shfl_xor(den0, m, 64); den1 += __shfl_xor(den1, m, 64);
    den2 += __shfl_xor(den2, m, 64);
    a00 += __shfl_xor(a00, m, 64); a01 += __shfl_xor(a01, m, 64);
    a10 += __shfl_xor(a10, m, 64); a11 += __shfl_xor(a11, m, 64);
    a20 += __shfl_xor(a20, m, 64); a21 += __shfl_xor(a21, m, 64);
  }
  if (valid && sub == 0) {
    float l0 = (a00/den0 + a10/den1 + a20/den2) * (1.f/3.f) + b2[0];
    float l1 = (a01/den0 + a11/den1 + a21/den2) * (1.f/3.f) + b2[1];
    float m = fmaxf(l0, l1);
    float e0 = __expf(l0 - m), e1 = __expf(l1 - m);
    float inv = 1.f / (e0 + e1);
    *(float2*)(outp + (size_t)d * 2) = make_float2(e0 * inv, e1 * inv);
  }
}

extern "C" void kernel_launch(void* const* d_in, const int* in_sizes, int n_in,
                              void* d_out, int out_size, void* d_ws, size_t ws_size,
                              hipStream_t stream) {
  const float* x   = (const float*)d_in[0];
  const int*   ei  = (const int*)d_in[1];
  const float* W1  = (const float*)d_in[2];
  const float* as1 = (const float*)d_in[3];
  const float* ad1 = (const float*)d_in[4];
  const float* b1  = (const float*)d_in[5];
  const float* fcW = (const float*)d_in[6];
  const float* fcb = (const float*)d_in[7];
  const float* W2  = (const float*)d_in[8];
  const float* as2 = (const float*)d_in[9];
  const float* ad2 = (const float*)d_in[10];
  const float* b2  = (const float*)d_in[11];
  float* outp = (float*)d_out;

  const int Nn   = in_sizes[0] / 128;
  const int E    = in_sizes[1] / 2;
  const int Etot = E + Nn;
  const int* esrc = ei;
  const int* edst = ei + E;

  char* p = (char*)d_ws;
  auto alloc = [&](size_t bytes) {
    char* q = p; p += (bytes + 255) & ~(size_t)255; return q;
  };
  ushort_t* h1bf = (ushort_t*)alloc((size_t)Nn * 192 * 2);  // later reused as hfc
  float* out1  = (float*)alloc((size_t)Nn * 192 * 4);       // later reused as pk
  float* a1s   = (float*)alloc((size_t)Nn * 3 * 4);
  float* a1d   = (float*)alloc((size_t)Nn * 3 * 4);
  int* deg     = (int*)alloc((size_t)Nn * 4);
  int* off     = (int*)alloc((size_t)(Nn + 1) * 4);
  int* cursor  = (int*)alloc((size_t)Nn * 4);
  int* texcl   = (int*)alloc((size_t)Nn * 4);
  int* bsum    = (int*)alloc(512 * 4);
  int* boff    = (int*)alloc(512 * 4);
  int* csr     = (int*)alloc((size_t)Etot * 4);
  float* hfc = (float*)h1bf;             // [N,64] f32 fits in h1bf's 38 MB
  float* pk  = out1;                     // [N,12] packed h2/a2s/a2d

  hipMemsetAsync(deg, 0, (size_t)Nn * 4, stream);

  const int mb = (Nn + 255) / 256;
  const int nb4 = (Nn + 3) / 4;
  const int eb = (Etot + 255) / 256;
  const int sb = (Nn + 255) / 256;

  // 1. h1(bf16) = x @ W1, fused: a1s/a1d per-row attention dots (f32)
  gemm256<true, true, false, false><<<dim3(mb, 3), 256, 0, stream>>>(
      x, W1, nullptr, h1bf, a1s, a1d, as1, ad1, Nn, 192, 128);

  // 2. CSR build (dst-sorted src list), shared by both layers
  edge_count<<<eb, 256, 0, stream>>>(edst, deg, E, Etot);
  scan1<<<sb, 256, 0, stream>>>(deg, texcl, bsum, Nn);
  scan2<<<1, 512, 0, stream>>>(bsum, boff, sb);
  scan3<<<sb, 256, 0, stream>>>(texcl, boff, off, cursor, Nn, Etot);
  edge_fill<<<eb, 256, 0, stream>>>(esrc, edst, cursor, csr, E, Etot);

  // 3. layer-1 softmax aggregation (+bias)
  agg1_kernel<<<nb4, 256, 0, stream>>>(h1bf, a1s, a1d, off, csr, b1, out1, Nn);

  // 4. hfc = relu(out1 @ fcW + fcb)   [N,64]
  gemm256<false, false, true, true><<<dim3(mb, 1), 256, 0, stream>>>(
      out1, fcW, fcb, hfc, nullptr, nullptr, nullptr, nullptr, Nn, 64, 192);

  // 5. pk = [hfc @ W2, a2s, a2d] packed per node
  gemm2_pack<<<nb4, 256, 0, stream>>>(hfc, W2, as2, ad2, pk, Nn);

  // 6. layer-2 aggregation + head mean + bias + softmax -> output
  agg2_kernel<<<(Nn + 31) / 32, 256, 0, stream>>>(pk, off, csr, b2, outp, Nn);
}

// Round 12
// 535.603 us; speedup vs baseline: 1.3221x; 1.1955x over previous
//
#include <hip/hip_runtime.h>
#include <cstdint>
#include <cstddef>

typedef unsigned short ushort_t;
typedef unsigned short ushort8 __attribute__((ext_vector_type(8)));

#define LRELU(x) ((x) > 0.f ? (x) : 0.2f*(x))

__device__ __forceinline__ float bf2f(ushort_t u) {
  return __uint_as_float(((unsigned int)u) << 16);
}
__device__ __forceinline__ ushort_t f2bf(float f) {
  unsigned int b = __float_as_uint(f);
  b += 0x7fffu + ((b >> 16) & 1u);
  return (ushort_t)(b >> 16);
}
__device__ __forceinline__ float readlane_f(float v, int l) {
  return __uint_as_float(__builtin_amdgcn_readlane(__float_as_uint(v), l));
}

__device__ __forceinline__ float wave_reduce(float v) {
  #pragma unroll
  for (int m = 32; m > 0; m >>= 1) v += __shfl_xor(v, m, 64);
  return v;
}

// ---- 256x64-tile f32 GEMM, 8x8 micro-tile. C[M,N] = A[M,K] @ B[K,N] --------
// blockIdx.y = 64-col block (== head for gemm1). Optional fused epilogue:
//  BF16OUT: store C as bf16;  ATT: also emit per-row dot(C_row, atts/attd)
//  (valid because one block covers the full 64-col head).
template<bool BF16OUT, bool ATT, bool RELU, bool BIAS>
__global__ __launch_bounds__(256) void gemm256(const float* __restrict__ A,
    const float* __restrict__ Bm, const float* __restrict__ bias,
    void* __restrict__ Cout, float* __restrict__ a_s, float* __restrict__ a_d,
    const float* __restrict__ atts, const float* __restrict__ attd,
    int M, int N, int K) {
  __shared__ float As[32][260];   // [k][row], pad 260: f4-aligned, 2-way-only banks
  __shared__ float Bs[32][68];    // [k][col]
  const int tid = threadIdx.x;
  const int tx = tid & 7;         // col group (8 cols)
  const int ty = tid >> 3;        // row group (8 rows), 0..31
  const int r0 = blockIdx.x * 256;
  const int c0 = blockIdx.y * 64;
  float acc[8][8] = {};
  for (int k0 = 0; k0 < K; k0 += 32) {
    #pragma unroll
    for (int i = 0; i < 8; i++) {              // A tile: 2048 float4
      int f = tid + i * 256;
      int row = f >> 3, k4 = (f & 7) << 2;
      float4 v = make_float4(0.f, 0.f, 0.f, 0.f);
      int gr = r0 + row;
      if (gr < M) v = *(const float4*)(A + (size_t)gr * K + k0 + k4);
      As[k4 + 0][row] = v.x; As[k4 + 1][row] = v.y;
      As[k4 + 2][row] = v.z; As[k4 + 3][row] = v.w;
    }
    #pragma unroll
    for (int i = 0; i < 2; i++) {              // B tile: 512 float4
      int f = tid + i * 256;
      int kr = f >> 4, c4 = (f & 15) << 2;
      *(float4*)&Bs[kr][c4] = *(const float4*)(Bm + (size_t)(k0 + kr) * N + c0 + c4);
    }
    __syncthreads();
    #pragma unroll
    for (int kk = 0; kk < 32; kk++) {
      float a[8], b[8];
      *(float4*)&a[0] = *(const float4*)&As[kk][ty * 8];
      *(float4*)&a[4] = *(const float4*)&As[kk][ty * 8 + 4];
      *(float4*)&b[0] = *(const float4*)&Bs[kk][tx * 8];
      *(float4*)&b[4] = *(const float4*)&Bs[kk][tx * 8 + 4];
      #pragma unroll
      for (int i = 0; i < 8; i++)
        #pragma unroll
        for (int j = 0; j < 8; j++)
          acc[i][j] = fmaf(a[i], b[j], acc[i][j]);
    }
    __syncthreads();
  }
  float vs[8], vd[8], bb[8];
  if (ATT) {
    #pragma unroll
    for (int j = 0; j < 8; j++) {
      vs[j] = atts[c0 + tx * 8 + j];
      vd[j] = attd[c0 + tx * 8 + j];
    }
  }
  if (BIAS) {
    #pragma unroll
    for (int j = 0; j < 8; j++) bb[j] = bias[c0 + tx * 8 + j];
  }
  #pragma unroll
  for (int i = 0; i < 8; i++) {
    int r = r0 + ty * 8 + i;
    bool ok = r < M;
    if (ATT) {   // per-row attention dots (f32, pre-rounding); reduce over tx
      float ps = 0.f, pd = 0.f;
      #pragma unroll
      for (int j = 0; j < 8; j++) {
        ps = fmaf(acc[i][j], vs[j], ps);
        pd = fmaf(acc[i][j], vd[j], pd);
      }
      #pragma unroll
      for (int m = 1; m < 8; m <<= 1) {   // xor within tx-group: same r per group
        ps += __shfl_xor(ps, m, 64);
        pd += __shfl_xor(pd, m, 64);
      }
      if (ok && tx == 0) {
        a_s[r * 3 + blockIdx.y] = ps;
        a_d[r * 3 + blockIdx.y] = pd;
      }
    }
    if (!ok) continue;
    if (BF16OUT) {
      ushort8 u;
      #pragma unroll
      for (int j = 0; j < 8; j++) u[j] = f2bf(acc[i][j]);
      *(ushort8*)((ushort_t*)Cout + (size_t)r * N + c0 + tx * 8) = u;
    } else {
      float o[8];
      #pragma unroll
      for (int j = 0; j < 8; j++) {
        o[j] = acc[i][j];
        if (BIAS) o[j] += bb[j];
        if (RELU) o[j] = fmaxf(o[j], 0.f);
      }
      float* cp = (float*)Cout + (size_t)r * N + c0 + tx * 8;
      *(float4*)cp = make_float4(o[0], o[1], o[2], o[3]);
      *(float4*)(cp + 4) = make_float4(o[4], o[5], o[6], o[7]);
    }
  }
}

// ---------------- CSR build (shared by both GAT layers) ---------------------
// Pass 1: count AND capture per-edge rank (old value of the counter).
__global__ void edge_rank(const int* __restrict__ dst, int* __restrict__ deg,
                          int* __restrict__ rank, int E, int Etot) {
  int e = blockIdx.x * 256 + threadIdx.x;
  if (e >= Etot) return;
  int d = (e < E) ? dst[e] : (e - E);
  rank[e] = atomicAdd(&deg[d], 1);
}

__global__ void scan1(const int* __restrict__ deg, int* __restrict__ excl,
                      int* __restrict__ bsum, int n) {
  __shared__ int sh[256];
  int t = threadIdx.x;
  int idx = blockIdx.x * 256 + t;
  int v = (idx < n) ? deg[idx] : 0;
  sh[t] = v;
  __syncthreads();
  for (int ofs = 1; ofs < 256; ofs <<= 1) {
    int add = (t >= ofs) ? sh[t - ofs] : 0;
    __syncthreads();
    sh[t] += add;
    __syncthreads();
  }
  if (idx < n) excl[idx] = sh[t] - v;
  if (t == 255) bsum[blockIdx.x] = sh[255];
}

__global__ void scan2(const int* __restrict__ bsum, int* __restrict__ boff, int nb) {
  __shared__ int sh[512];
  int t = threadIdx.x;
  int v = (t < nb) ? bsum[t] : 0;
  sh[t] = v;
  __syncthreads();
  for (int ofs = 1; ofs < 512; ofs <<= 1) {
    int add = (t >= ofs) ? sh[t - ofs] : 0;
    __syncthreads();
    sh[t] += add;
    __syncthreads();
  }
  if (t < nb) boff[t] = sh[t] - v;
}

__global__ void scan3(const int* __restrict__ excl, const int* __restrict__ boff,
                      int* __restrict__ off, int n, int etot) {
  int idx = blockIdx.x * 256 + threadIdx.x;
  if (idx < n) off[idx] = excl[idx] + boff[blockIdx.x];
  if (idx == 0) off[n] = etot;
}

// Pass 2: place edges with NO atomic — position = off[dst] + rank.
__global__ void edge_place(const int* __restrict__ src, const int* __restrict__ dst,
                           const int* __restrict__ rank, const int* __restrict__ off,
                           int* __restrict__ csr, int E, int Etot) {
  int e = blockIdx.x * 256 + threadIdx.x;
  if (e >= Etot) return;
  int s, d;
  if (e < E) { s = src[e]; d = dst[e]; } else { s = d = e - E; }
  csr[off[d] + rank[e]] = s;
}

// ------- layer-1 softmax-aggregation: out[d] = (sum ex*h1[s])/(sum ex) + b --
// One wave per dst node; lane = channel. h1 gathered as bf16.
// Exp/LeakyReLU/a1s-gather hoisted to the lane-parallel prefetch phase;
// inner loop broadcasts via readlane (SALU) -> SGPR base addresses.
__global__ __launch_bounds__(256) void agg1_kernel(const ushort_t* __restrict__ h1,
    const float* __restrict__ a1s, const float* __restrict__ a1d,
    const int* __restrict__ off, const int* __restrict__ csr,
    const float* __restrict__ b1, float* __restrict__ out, int n) {
  int wid = (blockIdx.x * 256 + threadIdx.x) >> 6;
  int lane = threadIdx.x & 63;
  if (wid >= n) return;
  float ad0 = a1d[wid * 3 + 0], ad1 = a1d[wid * 3 + 1], ad2 = a1d[wid * 3 + 2];
  int start = off[wid], end = off[wid + 1];
  float acc0 = 0.f, acc1 = 0.f, acc2 = 0.f;
  float den0 = 0.f, den1 = 0.f, den2 = 0.f;
  for (int base = start; base < end; base += 64) {
    int cnt = min(end - base, 64);
    int sv = 0;
    float px0 = 0.f, px1 = 0.f, px2 = 0.f;
    if (lane < cnt) {                       // lane-parallel per-edge coeffs
      sv = csr[base + lane];
      px0 = __expf(LRELU(a1s[sv * 3 + 0] + ad0));
      px1 = __expf(LRELU(a1s[sv * 3 + 1] + ad1));
      px2 = __expf(LRELU(a1s[sv * 3 + 2] + ad2));
      den0 += px0; den1 += px1; den2 += px2;
    }
    int j = 0;
    for (; j + 1 < cnt; j += 2) {           // unroll-2 for load ILP
      int sA = __builtin_amdgcn_readlane(sv, j);
      int sB = __builtin_amdgcn_readlane(sv, j + 1);
      float xA0 = readlane_f(px0, j), xA1 = readlane_f(px1, j), xA2 = readlane_f(px2, j);
      float xB0 = readlane_f(px0, j+1), xB1 = readlane_f(px1, j+1), xB2 = readlane_f(px2, j+1);
      const ushort_t* hA = h1 + (size_t)sA * 192;
      const ushort_t* hB = h1 + (size_t)sB * 192;
      float a0 = bf2f(hA[lane]), a1v = bf2f(hA[64 + lane]), a2v = bf2f(hA[128 + lane]);
      float b0 = bf2f(hB[lane]), b1v = bf2f(hB[64 + lane]), b2v = bf2f(hB[128 + lane]);
      acc0 = fmaf(xA0, a0, acc0); acc1 = fmaf(xA1, a1v, acc1); acc2 = fmaf(xA2, a2v, acc2);
      acc0 = fmaf(xB0, b0, acc0); acc1 = fmaf(xB1, b1v, acc1); acc2 = fmaf(xB2, b2v, acc2);
    }
    if (j < cnt) {                          // odd tail
      int sA = __builtin_amdgcn_readlane(sv, j);
      float xA0 = readlane_f(px0, j), xA1 = readlane_f(px1, j), xA2 = readlane_f(px2, j);
      const ushort_t* hA = h1 + (size_t)sA * 192;
      acc0 = fmaf(xA0, bf2f(hA[lane]),       acc0);
      acc1 = fmaf(xA1, bf2f(hA[64 + lane]),  acc1);
      acc2 = fmaf(xA2, bf2f(hA[128 + lane]), acc2);
    }
  }
  den0 = wave_reduce(den0); den1 = wave_reduce(den1); den2 = wave_reduce(den2);
  size_t o = (size_t)wid * 192;
  out[o + lane]       = acc0 / den0 + b1[lane];
  out[o + 64 + lane]  = acc1 / den1 + b1[64 + lane];
  out[o + 128 + lane] = acc2 / den2 + b1[128 + lane];
}

// --- layer-2 GEMM [N,64]@[64,6] + a2 coeffs -> packed 12-float rows ---------
// pk[d] = [h2(6), a2s(3), a2d(3)]; wave per node.
__global__ __launch_bounds__(256) void gemm2_pack(const float* __restrict__ hfc,
    const float* __restrict__ W2, const float* __restrict__ as2,
    const float* __restrict__ ad2, float* __restrict__ pk, int n) {
  int wid = (blockIdx.x * 256 + threadIdx.x) >> 6;
  int lane = threadIdx.x & 63;
  if (wid >= n) return;
  float hv = hfc[(size_t)wid * 64 + lane];
  float o[6];
  #pragma unroll
  for (int j = 0; j < 6; j++) o[j] = wave_reduce(hv * W2[lane * 6 + j]);
  if (lane == 0) {
    float* pp = pk + (size_t)wid * 12;
    *(float4*)pp = make_float4(o[0], o[1], o[2], o[3]);
    *(float4*)(pp + 4) = make_float4(o[4], o[5],
        o[0]*as2[0] + o[1]*as2[1], o[2]*as2[2] + o[3]*as2[3]);
    *(float4*)(pp + 8) = make_float4(o[4]*as2[4] + o[5]*as2[5],
        o[0]*ad2[0] + o[1]*ad2[1], o[2]*ad2[2] + o[3]*ad2[3],
        o[4]*ad2[4] + o[5]*ad2[5]);
  }
}

// --- layer-2 aggregation + head mean + bias + 2-way softmax -----------------
// 8 lanes per node (edge-parallel), 8 nodes per wave; packed 48B gather/edge.
__global__ __launch_bounds__(256) void agg2_kernel(const float* __restrict__ pk,
    const int* __restrict__ off, const int* __restrict__ csr,
    const float* __restrict__ b2, float* __restrict__ outp, int n) {
  int wave = (blockIdx.x * 256 + threadIdx.x) >> 6;
  int lane = threadIdx.x & 63;
  int g = lane >> 3, sub = lane & 7;
  int d = wave * 8 + g;
  bool valid = d < n;
  float ad0 = 0.f, ad1 = 0.f, ad2v = 0.f;
  int start = 0, end = 0;
  if (valid) {
    const float* pd = pk + (size_t)d * 12;
    ad0 = pd[9]; ad1 = pd[10]; ad2v = pd[11];
    start = off[d]; end = off[d + 1];
  }
  float den0 = 0.f, den1 = 0.f, den2 = 0.f;
  float a00 = 0.f, a01 = 0.f, a10 = 0.f, a11 = 0.f, a20 = 0.f, a21 = 0.f;
  for (int j = start + sub; j < end; j += 8) {
    int s = csr[j];
    const float* ps = pk + (size_t)s * 12;
    float4 A = *(const float4*)ps;        // h2[0..3]
    float4 B = *(const float4*)(ps + 4);  // h2[4], h2[5], a2s0, a2s1
    float  c = ps[8];                     // a2s2
    float x0 = __expf(LRELU(B.z + ad0));
    float x1 = __expf(LRELU(B.w + ad1));
    float x2 = __expf(LRELU(c   + ad2v));
    den0 += x0; den1 += x1; den2 += x2;
    a00 = fmaf(x0, A.x, a00); a01 = fmaf(x0, A.y, a01);
    a10 = fmaf(x1, A.z, a10); a11 = fmaf(x1, A.w, a11);
    a20 = fmaf(x2, B.x, a20); a21 = fmaf(x2, B.y, a21);
  }
  #pragma unroll
  for (int m = 1; m < 8; m <<= 1) {   // reduce within 8-lane group
    den0 += __shfl_xor(den0, m, 64); den1 += __shfl_xor(den1, m, 64);
    den2 += __shfl_xor(den2, m, 64);
    a00 += __shfl_xor(a00, m, 64); a01 += __shfl_xor(a01, m, 64);
    a10 += __shfl_xor(a10, m, 64); a11 += __shfl_xor(a11, m, 64);
    a20 += __shfl_xor(a20, m, 64); a21 += __shfl_xor(a21, m, 64);
  }
  if (valid && sub == 0) {
    float l0 = (a00/den0 + a10/den1 + a20/den2) * (1.f/3.f) + b2[0];
    float l1 = (a01/den0 + a11/den1 + a21/den2) * (1.f/3.f) + b2[1];
    float m = fmaxf(l0, l1);
    float e0 = __expf(l0 - m), e1 = __expf(l1 - m);
    float inv = 1.f / (e0 + e1);
    *(float2*)(outp + (size_t)d * 2) = make_float2(e0 * inv, e1 * inv);
  }
}

extern "C" void kernel_launch(void* const* d_in, const int* in_sizes, int n_in,
                              void* d_out, int out_size, void* d_ws, size_t ws_size,
                              hipStream_t stream) {
  const float* x   = (const float*)d_in[0];
  const int*   ei  = (const int*)d_in[1];
  const float* W1  = (const float*)d_in[2];
  const float* as1 = (const float*)d_in[3];
  const float* ad1 = (const float*)d_in[4];
  const float* b1  = (const float*)d_in[5];
  const float* fcW = (const float*)d_in[6];
  const float* fcb = (const float*)d_in[7];
  const float* W2  = (const float*)d_in[8];
  const float* as2 = (const float*)d_in[9];
  const float* ad2 = (const float*)d_in[10];
  const float* b2  = (const float*)d_in[11];
  float* outp = (float*)d_out;

  const int Nn   = in_sizes[0] / 128;
  const int E    = in_sizes[1] / 2;
  const int Etot = E + Nn;
  const int* esrc = ei;
  const int* edst = ei + E;

  char* p = (char*)d_ws;
  auto alloc = [&](size_t bytes) {
    char* q = p; p += (bytes + 255) & ~(size_t)255; return q;
  };
  ushort_t* h1bf = (ushort_t*)alloc((size_t)Nn * 192 * 2);  // later reused as hfc
  float* out1  = (float*)alloc((size_t)Nn * 192 * 4);       // later reused as pk
  float* a1s   = (float*)alloc((size_t)Nn * 3 * 4);
  float* a1d   = (float*)alloc((size_t)Nn * 3 * 4);
  int* deg     = (int*)alloc((size_t)Nn * 4);
  int* off     = (int*)alloc((size_t)(Nn + 1) * 4);
  int* texcl   = (int*)alloc((size_t)Nn * 4);
  int* bsum    = (int*)alloc(512 * 4);
  int* boff    = (int*)alloc(512 * 4);
  int* csr     = (int*)alloc((size_t)Etot * 4);
  int* rank    = (int*)alloc((size_t)Etot * 4);
  float* hfc = (float*)h1bf;             // [N,64] f32 fits in h1bf's 38 MB
  float* pk  = out1;                     // [N,12] packed h2/a2s/a2d

  hipMemsetAsync(deg, 0, (size_t)Nn * 4, stream);

  const int mb = (Nn + 255) / 256;
  const int nb4 = (Nn + 3) / 4;
  const int eb = (Etot + 255) / 256;
  const int sb = (Nn + 255) / 256;

  // 1. h1(bf16) = x @ W1, fused: a1s/a1d per-row attention dots (f32)
  gemm256<true, true, false, false><<<dim3(mb, 3), 256, 0, stream>>>(
      x, W1, nullptr, h1bf, a1s, a1d, as1, ad1, Nn, 192, 128);

  // 2. CSR build (dst-sorted src list), shared by both layers.
  //    Atomic pass captures rank; placement pass is atomic-free.
  edge_rank<<<eb, 256, 0, stream>>>(edst, deg, rank, E, Etot);
  scan1<<<sb, 256, 0, stream>>>(deg, texcl, bsum, Nn);
  scan2<<<1, 512, 0, stream>>>(bsum, boff, sb);
  scan3<<<sb, 256, 0, stream>>>(texcl, boff, off, Nn, Etot);
  edge_place<<<eb, 256, 0, stream>>>(esrc, edst, rank, off, csr, E, Etot);

  // 3. layer-1 softmax aggregation (+bias)
  agg1_kernel<<<nb4, 256, 0, stream>>>(h1bf, a1s, a1d, off, csr, b1, out1, Nn);

  // 4. hfc = relu(out1 @ fcW + fcb)   [N,64]
  gemm256<false, false, true, true><<<dim3(mb, 1), 256, 0, stream>>>(
      out1, fcW, fcb, hfc, nullptr, nullptr, nullptr, nullptr, Nn, 64, 192);

  // 5. pk = [hfc @ W2, a2s, a2d] packed per node
  gemm2_pack<<<nb4, 256, 0, stream>>>(hfc, W2, as2, ad2, pk, Nn);

  // 6. layer-2 aggregation + head mean + bias + softmax -> output
  agg2_kernel<<<(Nn + 31) / 32, 256, 0, stream>>>(pk, off, csr, b2, outp, Nn);
}

// Round 14
// 490.254 us; speedup vs baseline: 1.4444x; 1.0925x over previous
//
#include <hip/hip_runtime.h>
#include <cstdint>
#include <cstddef>

typedef unsigned short ushort_t;
typedef unsigned short ushort8 __attribute__((ext_vector_type(8)));

#define LRELU(x) ((x) > 0.f ? (x) : 0.2f*(x))

__device__ __forceinline__ float bf2f(ushort_t u) {
  return __uint_as_float(((unsigned int)u) << 16);
}
__device__ __forceinline__ float bflo(unsigned int u) {
  return __uint_as_float(u << 16);
}
__device__ __forceinline__ float bfhi(unsigned int u) {
  return __uint_as_float(u & 0xffff0000u);
}
__device__ __forceinline__ ushort_t f2bf(float f) {
  unsigned int b = __float_as_uint(f);
  b += 0x7fffu + ((b >> 16) & 1u);
  return (ushort_t)(b >> 16);
}
__device__ __forceinline__ float readlane_f(float v, int l) {
  return __uint_as_float(__builtin_amdgcn_readlane(__float_as_uint(v), l));
}

__device__ __forceinline__ float wave_reduce(float v) {
  #pragma unroll
  for (int m = 32; m > 0; m >>= 1) v += __shfl_xor(v, m, 64);
  return v;
}

// ---- 256x64-tile f32 GEMM, 8x8 micro-tile. C[M,N] = A[M,K] @ B[K,N] --------
// EDGE: blocks >= 3*mb instead run the CSR rank pass (atomic), hiding its
//       latency under GEMM compute (block-uniform early return, pre-barrier).
// PACK: epilogue computes pk[r] = [C_row@W2 (6), a2s(3), a2d(3)] per row.
// ATT:  emit per-row dot(C_row, atts/attd) (one block covers the 64-col head).
template<bool BF16OUT, bool ATT, bool RELU, bool BIAS, bool EDGE, bool PACK>
__global__ __launch_bounds__(256) void gemm256(const float* __restrict__ A,
    const float* __restrict__ Bm, const float* __restrict__ bias,
    void* __restrict__ Cout, float* __restrict__ a_s, float* __restrict__ a_d,
    const float* __restrict__ atts, const float* __restrict__ attd,
    int M, int N, int K, int mb,
    const int* __restrict__ edst, int* __restrict__ deg, int* __restrict__ rank,
    int E, int Etot,
    const float* __restrict__ W2, const float* __restrict__ as2,
    const float* __restrict__ ad2, float* __restrict__ pk) {
  __shared__ float As[32][260];   // [k][row], pad 260: f4-aligned, 2-way-only banks
  __shared__ float Bs[32][68];    // [k][col]
  const int tid = threadIdx.x;
  int bx, by;
  if (EDGE) {
    int bid = blockIdx.x;
    if (bid >= 3 * mb) {          // edge-rank blocks (gemm1 has 3 col-blocks)
      int e = (bid - 3 * mb) * 256 + tid;
      if (e < Etot) {
        int d = (e < E) ? edst[e] : (e - E);
        rank[e] = atomicAdd(&deg[d], 1);
      }
      return;                      // block-uniform: before any barrier
    }
    bx = bid % mb; by = bid / mb;
  } else { bx = blockIdx.x; by = blockIdx.y; }
  const int tx = tid & 7;         // col group (8 cols)
  const int ty = tid >> 3;        // row group (8 rows), 0..31
  const int r0 = bx * 256;
  const int c0 = by * 64;
  float acc[8][8] = {};
  for (int k0 = 0; k0 < K; k0 += 32) {
    #pragma unroll
    for (int i = 0; i < 8; i++) {              // A tile: 2048 float4
      int f = tid + i * 256;
      int row = f >> 3, k4 = (f & 7) << 2;
      float4 v = make_float4(0.f, 0.f, 0.f, 0.f);
      int gr = r0 + row;
      if (gr < M) v = *(const float4*)(A + (size_t)gr * K + k0 + k4);
      As[k4 + 0][row] = v.x; As[k4 + 1][row] = v.y;
      As[k4 + 2][row] = v.z; As[k4 + 3][row] = v.w;
    }
    #pragma unroll
    for (int i = 0; i < 2; i++) {              // B tile: 512 float4
      int f = tid + i * 256;
      int kr = f >> 4, c4 = (f & 15) << 2;
      *(float4*)&Bs[kr][c4] = *(const float4*)(Bm + (size_t)(k0 + kr) * N + c0 + c4);
    }
    __syncthreads();
    #pragma unroll
    for (int kk = 0; kk < 32; kk++) {
      float a[8], b[8];
      *(float4*)&a[0] = *(const float4*)&As[kk][ty * 8];
      *(float4*)&a[4] = *(const float4*)&As[kk][ty * 8 + 4];
      *(float4*)&b[0] = *(const float4*)&Bs[kk][tx * 8];
      *(float4*)&b[4] = *(const float4*)&Bs[kk][tx * 8 + 4];
      #pragma unroll
      for (int i = 0; i < 8; i++)
        #pragma unroll
        for (int j = 0; j < 8; j++)
          acc[i][j] = fmaf(a[i], b[j], acc[i][j]);
    }
    __syncthreads();
  }
  float vs[8], vd[8], bb[8];
  if (ATT) {
    #pragma unroll
    for (int j = 0; j < 8; j++) {
      vs[j] = atts[c0 + tx * 8 + j];
      vd[j] = attd[c0 + tx * 8 + j];
    }
  }
  if (BIAS) {
    #pragma unroll
    for (int j = 0; j < 8; j++) bb[j] = bias[c0 + tx * 8 + j];
  }
  #pragma unroll
  for (int i = 0; i < 8; i++) {
    int r = r0 + ty * 8 + i;
    bool ok = r < M;
    if (ATT) {   // per-row attention dots (f32, pre-rounding); reduce over tx
      float ps = 0.f, pd = 0.f;
      #pragma unroll
      for (int j = 0; j < 8; j++) {
        ps = fmaf(acc[i][j], vs[j], ps);
        pd = fmaf(acc[i][j], vd[j], pd);
      }
      #pragma unroll
      for (int m = 1; m < 8; m <<= 1) {   // xor within tx-group: same r per group
        ps += __shfl_xor(ps, m, 64);
        pd += __shfl_xor(pd, m, 64);
      }
      if (ok && tx == 0) {
        a_s[r * 3 + by] = ps;
        a_d[r * 3 + by] = pd;
      }
    }
    if (!ok) continue;
    if (BF16OUT) {
      ushort8 u;
      #pragma unroll
      for (int j = 0; j < 8; j++) u[j] = f2bf(acc[i][j]);
      *(ushort8*)((ushort_t*)Cout + (size_t)r * N + c0 + tx * 8) = u;
    } else {
      float o[8];
      #pragma unroll
      for (int j = 0; j < 8; j++) {
        o[j] = acc[i][j];
        if (BIAS) o[j] += bb[j];
        if (RELU) o[j] = fmaxf(o[j], 0.f);
      }
      float* cp = (float*)Cout + (size_t)r * N + c0 + tx * 8;
      *(float4*)cp = make_float4(o[0], o[1], o[2], o[3]);
      *(float4*)(cp + 4) = make_float4(o[4], o[5], o[6], o[7]);
    }
  }
  if (PACK) {   // fused layer-2 projection: pk[r] = [h2(6), a2s(3), a2d(3)]
    __syncthreads();               // make this block's C stores visible
    int r = r0 + tid;              // 256 threads <-> 256 rows (N == 64)
    if (r < M) {
      const float* hp = (const float*)Cout + (size_t)r * 64;
      float o[6] = {};
      #pragma unroll
      for (int k = 0; k < 64; k += 4) {
        float4 hv = *(const float4*)(hp + k);
        float h4[4] = {hv.x, hv.y, hv.z, hv.w};
        #pragma unroll
        for (int c = 0; c < 4; c++)
          #pragma unroll
          for (int j = 0; j < 6; j++)
            o[j] = fmaf(h4[c], W2[(k + c) * 6 + j], o[j]);
      }
      float* pp = pk + (size_t)r * 12;
      *(float4*)pp = make_float4(o[0], o[1], o[2], o[3]);
      *(float4*)(pp + 4) = make_float4(o[4], o[5],
          o[0]*as2[0] + o[1]*as2[1], o[2]*as2[2] + o[3]*as2[3]);
      *(float4*)(pp + 8) = make_float4(o[4]*as2[4] + o[5]*as2[5],
          o[0]*ad2[0] + o[1]*ad2[1], o[2]*ad2[2] + o[3]*ad2[3],
          o[4]*ad2[4] + o[5]*ad2[5]);
    }
  }
}

// ---------------- CSR scans + atomic-free placement -------------------------
__global__ void scan1(const int* __restrict__ deg, int* __restrict__ excl,
                      int* __restrict__ bsum, int n) {
  __shared__ int sh[256];
  int t = threadIdx.x;
  int idx = blockIdx.x * 256 + t;
  int v = (idx < n) ? deg[idx] : 0;
  sh[t] = v;
  __syncthreads();
  for (int ofs = 1; ofs < 256; ofs <<= 1) {
    int add = (t >= ofs) ? sh[t - ofs] : 0;
    __syncthreads();
    sh[t] += add;
    __syncthreads();
  }
  if (idx < n) excl[idx] = sh[t] - v;
  if (t == 255) bsum[blockIdx.x] = sh[255];
}

__global__ void scan2(const int* __restrict__ bsum, int* __restrict__ boff, int nb) {
  __shared__ int sh[512];
  int t = threadIdx.x;
  int v = (t < nb) ? bsum[t] : 0;
  sh[t] = v;
  __syncthreads();
  for (int ofs = 1; ofs < 512; ofs <<= 1) {
    int add = (t >= ofs) ? sh[t - ofs] : 0;
    __syncthreads();
    sh[t] += add;
    __syncthreads();
  }
  if (t < nb) boff[t] = sh[t] - v;
}

__global__ void scan3(const int* __restrict__ excl, const int* __restrict__ boff,
                      int* __restrict__ off, int n, int etot) {
  int idx = blockIdx.x * 256 + threadIdx.x;
  if (idx < n) off[idx] = excl[idx] + boff[blockIdx.x];
  if (idx == 0) off[n] = etot;
}

__global__ void edge_place(const int* __restrict__ src, const int* __restrict__ dst,
                           const int* __restrict__ rank, const int* __restrict__ off,
                           int* __restrict__ csr, int E, int Etot) {
  int e = blockIdx.x * 256 + threadIdx.x;
  if (e >= Etot) return;
  int s, d;
  if (e < E) { s = src[e]; d = dst[e]; } else { s = d = e - E; }
  csr[off[d] + rank[e]] = s;
}

// ------- layer-1 softmax-aggregation: out[d] = (sum ex*h1[s])/(sum ex) + b --
// One wave per dst node. Lane l (<48) owns 4 consecutive channels 4l..4l+3
// (head = l>>4): the per-edge gather is ONE dwordx2 wave-load (same cache
// lines as before, 1/3 the memory instructions). Coeffs computed lane-parallel
// in the prefetch phase, broadcast via readlane + 2 hoisted-mask selects.
__global__ __launch_bounds__(256) void agg1_kernel(const ushort_t* __restrict__ h1,
    const float* __restrict__ a1s, const float* __restrict__ a1d,
    const int* __restrict__ off, const int* __restrict__ csr,
    const float* __restrict__ b1, float* __restrict__ out, int n) {
  int wid = (blockIdx.x * 256 + threadIdx.x) >> 6;
  int lane = threadIdx.x & 63;
  if (wid >= n) return;
  float ad0 = a1d[wid * 3 + 0], ad1 = a1d[wid * 3 + 1], ad2 = a1d[wid * 3 + 2];
  int start = off[wid], end = off[wid + 1];
  const int co = (lane < 48 ? lane : 47) << 2;   // ushort offset of 4-ch group
  const bool s0 = lane < 16, s1 = lane < 32;     // head select masks (hoisted)
  float acc0 = 0.f, acc1 = 0.f, acc2 = 0.f, acc3 = 0.f;
  float den0 = 0.f, den1 = 0.f, den2 = 0.f;
  for (int base = start; base < end; base += 64) {
    int cnt = min(end - base, 64);
    int sv = 0;
    float px0 = 0.f, px1 = 0.f, px2 = 0.f;
    if (lane < cnt) {                       // lane-parallel per-edge coeffs
      sv = csr[base + lane];
      px0 = __expf(LRELU(a1s[sv * 3 + 0] + ad0));
      px1 = __expf(LRELU(a1s[sv * 3 + 1] + ad1));
      px2 = __expf(LRELU(a1s[sv * 3 + 2] + ad2));
      den0 += px0; den1 += px1; den2 += px2;
    }
    int j = 0;
    for (; j + 1 < cnt; j += 2) {           // unroll-2 for load ILP
      int sA = __builtin_amdgcn_readlane(sv, j);
      int sB = __builtin_amdgcn_readlane(sv, j + 1);
      float a0 = readlane_f(px0, j), a1v = readlane_f(px1, j), a2v = readlane_f(px2, j);
      float b0 = readlane_f(px0, j+1), b1v = readlane_f(px1, j+1), b2v = readlane_f(px2, j+1);
      float xA = s0 ? a0 : (s1 ? a1v : a2v);
      float xB = s0 ? b0 : (s1 ? b1v : b2v);
      uint2 uA = *(const uint2*)(h1 + (size_t)sA * 192 + co);
      uint2 uB = *(const uint2*)(h1 + (size_t)sB * 192 + co);
      acc0 = fmaf(xA, bflo(uA.x), acc0);
      acc1 = fmaf(xA, bfhi(uA.x), acc1);
      acc2 = fmaf(xA, bflo(uA.y), acc2);
      acc3 = fmaf(xA, bfhi(uA.y), acc3);
      acc0 = fmaf(xB, bflo(uB.x), acc0);
      acc1 = fmaf(xB, bfhi(uB.x), acc1);
      acc2 = fmaf(xB, bflo(uB.y), acc2);
      acc3 = fmaf(xB, bfhi(uB.y), acc3);
    }
    if (j < cnt) {                          // odd tail
      int sA = __builtin_amdgcn_readlane(sv, j);
      float a0 = readlane_f(px0, j), a1v = readlane_f(px1, j), a2v = readlane_f(px2, j);
      float xA = s0 ? a0 : (s1 ? a1v : a2v);
      uint2 uA = *(const uint2*)(h1 + (size_t)sA * 192 + co);
      acc0 = fmaf(xA, bflo(uA.x), acc0);
      acc1 = fmaf(xA, bfhi(uA.x), acc1);
      acc2 = fmaf(xA, bflo(uA.y), acc2);
      acc3 = fmaf(xA, bfhi(uA.y), acc3);
    }
  }
  den0 = wave_reduce(den0); den1 = wave_reduce(den1); den2 = wave_reduce(den2);
  if (lane < 48) {
    float den = s0 ? den0 : (s1 ? den1 : den2);
    float4 bb = *(const float4*)(b1 + (lane << 2));
    float* op = out + (size_t)wid * 192 + (lane << 2);
    *(float4*)op = make_float4(acc0 / den + bb.x, acc1 / den + bb.y,
                               acc2 / den + bb.z, acc3 / den + bb.w);
  }
}

// --- layer-2 aggregation + head mean + bias + 2-way softmax -----------------
// 8 lanes per node (edge-parallel), 8 nodes per wave; packed 48B gather/edge.
__global__ __launch_bounds__(256) void agg2_kernel(const float* __restrict__ pk,
    const int* __restrict__ off, const int* __restrict__ csr,
    const float* __restrict__ b2, float* __restrict__ outp, int n) {
  int wave = (blockIdx.x * 256 + threadIdx.x) >> 6;
  int lane = threadIdx.x & 63;
  int g = lane >> 3, sub = lane & 7;
  int d = wave * 8 + g;
  bool valid = d < n;
  float ad0 = 0.f, ad1 = 0.f, ad2v = 0.f;
  int start = 0, end = 0;
  if (valid) {
    const float* pd = pk + (size_t)d * 12;
    ad0 = pd[9]; ad1 = pd[10]; ad2v = pd[11];
    start = off[d]; end = off[d + 1];
  }
  float den0 = 0.f, den1 = 0.f, den2 = 0.f;
  float a00 = 0.f, a01 = 0.f, a10 = 0.f, a11 = 0.f, a20 = 0.f, a21 = 0.f;
  for (int j = start + sub; j < end; j += 8) {
    int s = csr[j];
    const float* ps = pk + (size_t)s * 12;
    float4 A = *(const float4*)ps;        // h2[0..3]
    float4 B = *(const float4*)(ps + 4);  // h2[4], h2[5], a2s0, a2s1
    float  c = ps[8];                     // a2s2
    float x0 = __expf(LRELU(B.z + ad0));
    float x1 = __expf(LRELU(B.w + ad1));
    float x2 = __expf(LRELU(c   + ad2v));
    den0 += x0; den1 += x1; den2 += x2;
    a00 = fmaf(x0, A.x, a00); a01 = fmaf(x0, A.y, a01);
    a10 = fmaf(x1, A.z, a10); a11 = fmaf(x1, A.w, a11);
    a20 = fmaf(x2, B.x, a20); a21 = fmaf(x2, B.y, a21);
  }
  #pragma unroll
  for (int m = 1; m < 8; m <<= 1) {   // reduce within 8-lane group
    den0 += __shfl_xor(den0, m, 64); den1 += __shfl_xor(den1, m, 64);
    den2 += __shfl_xor(den2, m, 64);
    a00 += __shfl_xor(a00, m, 64); a01 += __shfl_xor(a01, m, 64);
    a10 += __shfl_xor(a10, m, 64); a11 += __shfl_xor(a11, m, 64);
    a20 += __shfl_xor(a20, m, 64); a21 += __shfl_xor(a21, m, 64);
  }
  if (valid && sub == 0) {
    float l0 = (a00/den0 + a10/den1 + a20/den2) * (1.f/3.f) + b2[0];
    float l1 = (a01/den0 + a11/den1 + a21/den2) * (1.f/3.f) + b2[1];
    float m = fmaxf(l0, l1);
    float e0 = __expf(l0 - m), e1 = __expf(l1 - m);
    float inv = 1.f / (e0 + e1);
    *(float2*)(outp + (size_t)d * 2) = make_float2(e0 * inv, e1 * inv);
  }
}

extern "C" void kernel_launch(void* const* d_in, const int* in_sizes, int n_in,
                              void* d_out, int out_size, void* d_ws, size_t ws_size,
                              hipStream_t stream) {
  const float* x   = (const float*)d_in[0];
  const int*   ei  = (const int*)d_in[1];
  const float* W1  = (const float*)d_in[2];
  const float* as1 = (const float*)d_in[3];
  const float* ad1 = (const float*)d_in[4];
  const float* b1  = (const float*)d_in[5];
  const float* fcW = (const float*)d_in[6];
  const float* fcb = (const float*)d_in[7];
  const float* W2  = (const float*)d_in[8];
  const float* as2 = (const float*)d_in[9];
  const float* ad2 = (const float*)d_in[10];
  const float* b2  = (const float*)d_in[11];
  float* outp = (float*)d_out;

  const int Nn   = in_sizes[0] / 128;
  const int E    = in_sizes[1] / 2;
  const int Etot = E + Nn;
  const int* esrc = ei;
  const int* edst = ei + E;

  char* p = (char*)d_ws;
  auto alloc = [&](size_t bytes) {
    char* q = p; p += (bytes + 255) & ~(size_t)255; return q;
  };
  ushort_t* h1bf = (ushort_t*)alloc((size_t)Nn * 192 * 2);  // later reused as hfc
  float* out1  = (float*)alloc((size_t)Nn * 192 * 4);
  float* pk    = (float*)alloc((size_t)Nn * 12 * 4);        // own buffer: fc epilogue
  float* a1s   = (float*)alloc((size_t)Nn * 3 * 4);         // writes pk while other
  float* a1d   = (float*)alloc((size_t)Nn * 3 * 4);         // blocks still read out1
  int* deg     = (int*)alloc((size_t)Nn * 4);
  int* off     = (int*)alloc((size_t)(Nn + 1) * 4);
  int* texcl   = (int*)alloc((size_t)Nn * 4);
  int* bsum    = (int*)alloc(512 * 4);
  int* boff    = (int*)alloc(512 * 4);
  int* csr     = (int*)alloc((size_t)Etot * 4);
  int* rank    = (int*)alloc((size_t)Etot * 4);
  float* hfc = (float*)h1bf;             // [N,64] f32 fits in h1bf's 38 MB

  hipMemsetAsync(deg, 0, (size_t)Nn * 4, stream);

  const int mb = (Nn + 255) / 256;
  const int nb4 = (Nn + 3) / 4;
  const int eb = (Etot + 255) / 256;
  const int sb = (Nn + 255) / 256;

  // 1. h1(bf16) = x @ W1 (fused a1s/a1d dots)  ||  edge_rank (atomic) blocks
  gemm256<true, true, false, false, true, false><<<3 * mb + eb, 256, 0, stream>>>(
      x, W1, nullptr, h1bf, a1s, a1d, as1, ad1, Nn, 192, 128, mb,
      edst, deg, rank, E, Etot, nullptr, nullptr, nullptr, nullptr);

  // 2. offsets scan + atomic-free placement
  scan1<<<sb, 256, 0, stream>>>(deg, texcl, bsum, Nn);
  scan2<<<1, 512, 0, stream>>>(bsum, boff, sb);
  scan3<<<sb, 256, 0, stream>>>(texcl, boff, off, Nn, Etot);
  edge_place<<<eb, 256, 0, stream>>>(esrc, edst, rank, off, csr, E, Etot);

  // 3. layer-1 softmax aggregation (+bias)
  agg1_kernel<<<nb4, 256, 0, stream>>>(h1bf, a1s, a1d, off, csr, b1, out1, Nn);

  // 4. hfc = relu(out1 @ fcW + fcb), fused pk = [hfc@W2, a2s, a2d]
  gemm256<false, false, true, true, false, true><<<mb, 256, 0, stream>>>(
      out1, fcW, fcb, hfc, nullptr, nullptr, nullptr, nullptr, Nn, 64, 192, mb,
      nullptr, nullptr, nullptr, 0, 0, W2, as2, ad2, pk);

  // 5. layer-2 aggregation + head mean + bias + softmax -> output
  agg2_kernel<<<(Nn + 31) / 32, 256, 0, stream>>>(pk, off, csr, b2, outp, Nn);
}